// Round 1
// baseline (429.390 us; speedup 1.0000x reference)
//
#include <hip/hip_runtime.h>

#define D_DIM 2048
#define E_DIM 64

// GEMM config
#define BT 256      // tokens per block
#define DC 256      // D covered per block (split-D, 8 chunks)
#define DK 32       // LDS staging depth per iteration
#define XS 36       // padded LDS stride (floats)
#define WSTR 36

__global__ __launch_bounds__(256) void zero_kernel(float* __restrict__ logits,
                                                   float* __restrict__ ws_sums,
                                                   int n4) {
    int idx = blockIdx.x * blockDim.x + threadIdx.x;
    float4 z = make_float4(0.f, 0.f, 0.f, 0.f);
    for (int i = idx; i < n4; i += gridDim.x * blockDim.x)
        reinterpret_cast<float4*>(logits)[i] = z;
    if (blockIdx.x == 0 && threadIdx.x < 64) ws_sums[threadIdx.x] = 0.0f;
}

__global__ __launch_bounds__(256, 2) void router_gemm(const float* __restrict__ x,
                                                      const float* __restrict__ w,
                                                      float* __restrict__ logits) {
    __shared__ float xs[BT][XS];      // 36864 B
    __shared__ float wsh[E_DIM][WSTR]; // 9216 B
    const int tid = threadIdx.x;
    const int tbase = blockIdx.x * BT;
    const int dbase = blockIdx.y * DC;

    const int tt = tid & 31;   // token group (strided tokens tt + 32*i)
    const int te = tid >> 5;   // expert group (experts te*8 + j)

    float acc[8][8];
#pragma unroll
    for (int i = 0; i < 8; ++i)
#pragma unroll
        for (int j = 0; j < 8; ++j) acc[i][j] = 0.f;

    const int seg = tid & 7;
    const int r = tid >> 3;

    for (int kk = 0; kk < DC; kk += DK) {
        const int dpos = dbase + kk;
        // stage x tile: 256 rows x 32 floats
#pragma unroll
        for (int rr = 0; rr < BT; rr += 32) {
            int row = rr + r;
            float4 v = *reinterpret_cast<const float4*>(
                &x[(size_t)(tbase + row) * D_DIM + dpos + seg * 4]);
            *reinterpret_cast<float4*>(&xs[row][seg * 4]) = v;
        }
        // stage w tile: 64 rows x 32 floats
#pragma unroll
        for (int rr = 0; rr < E_DIM; rr += 32) {
            int row = rr + r;
            float4 v = *reinterpret_cast<const float4*>(
                &w[(size_t)row * D_DIM + dpos + seg * 4]);
            *reinterpret_cast<float4*>(&wsh[row][seg * 4]) = v;
        }
        __syncthreads();

#pragma unroll 1
        for (int d4 = 0; d4 < DK; d4 += 4) {
            float4 xv[8], wv[8];
#pragma unroll
            for (int i = 0; i < 8; ++i)
                xv[i] = *reinterpret_cast<const float4*>(&xs[tt + 32 * i][d4]);
#pragma unroll
            for (int j = 0; j < 8; ++j)
                wv[j] = *reinterpret_cast<const float4*>(&wsh[te * 8 + j][d4]);
#pragma unroll
            for (int i = 0; i < 8; ++i)
#pragma unroll
                for (int j = 0; j < 8; ++j) {
                    acc[i][j] = fmaf(xv[i].x, wv[j].x, acc[i][j]);
                    acc[i][j] = fmaf(xv[i].y, wv[j].y, acc[i][j]);
                    acc[i][j] = fmaf(xv[i].z, wv[j].z, acc[i][j]);
                    acc[i][j] = fmaf(xv[i].w, wv[j].w, acc[i][j]);
                }
        }
        __syncthreads();
    }

#pragma unroll
    for (int i = 0; i < 8; ++i) {
        size_t t = (size_t)(tbase + tt + 32 * i);
#pragma unroll
        for (int j = 0; j < 8; ++j)
            atomicAdd(&logits[t * E_DIM + te * 8 + j], acc[i][j]);
    }
}

__global__ __launch_bounds__(256) void postprocess(const float* __restrict__ logits,
                                                   float* __restrict__ out,
                                                   float* __restrict__ ws_sums,
                                                   int N) {
    const int lane = threadIdx.x & 63;
    const int wv = threadIdx.x >> 6;
    const size_t NE = (size_t)N * E_DIM;
    float* disp = out;
    float* comb = out + NE;
    float* probs_o = out + 3 * NE;
    float* idx_o = out + 4 * NE + 1;
    float* pn_o = out + 4 * NE + 1 + 2 * (size_t)N;

    float expsum = 0.f;  // per-lane (= per-expert) running sum of probs
    const int t0 = blockIdx.x * 64 + wv * 16;
    for (int k = 0; k < 16; ++k) {
        const int t = t0 + k;
        float l = logits[(size_t)t * E_DIM + lane];
        float m = l;
#pragma unroll
        for (int off = 32; off; off >>= 1) m = fmaxf(m, __shfl_xor(m, off));
        float p = __expf(l - m);
        float s = p;
#pragma unroll
        for (int off = 32; off; off >>= 1) s += __shfl_xor(s, off);
        float prob = p / s;
        probs_o[(size_t)t * E_DIM + lane] = prob;
        expsum += prob;

        // top-1: key = prob bits (positive -> order preserving) | (63-lane) for
        // lowest-index tie-break (matches jax.lax.top_k)
        unsigned long long key =
            ((unsigned long long)__float_as_uint(prob) << 32) | (unsigned)(63 - lane);
        unsigned long long k1 = key;
#pragma unroll
        for (int off = 32; off; off >>= 1) {
            unsigned long long o = __shfl_xor(k1, off);
            if (o > k1) k1 = o;
        }
        int i1 = 63 - (int)(k1 & 63);
        float p1 = __uint_as_float((unsigned)(k1 >> 32));

        unsigned long long k2 = (lane == i1) ? 0ull : key;
#pragma unroll
        for (int off = 32; off; off >>= 1) {
            unsigned long long o = __shfl_xor(k2, off);
            if (o > k2) k2 = o;
        }
        int i2 = 63 - (int)(k2 & 63);
        float p2 = __uint_as_float((unsigned)(k2 >> 32));

        float inv12 = 1.0f / (p1 + p2);
        float pn1 = p1 * inv12, pn2 = p2 * inv12;

        float dval = (lane == i1) ? pn1 : ((lane == i2) ? pn2 : 0.0f);
        disp[(size_t)t * E_DIM + lane] = dval;
        comb[(size_t)t * E_DIM + lane] = dval;
        if (lane == 0) {
            idx_o[2 * t] = (float)i1;
            idx_o[2 * t + 1] = (float)i2;
            pn_o[2 * t] = pn1;
            pn_o[2 * t + 1] = pn2;
        }
    }

    __shared__ float aux_s[4][64];
    aux_s[wv][lane] = expsum;
    __syncthreads();
    if (threadIdx.x < 64) {
        float s = aux_s[0][threadIdx.x] + aux_s[1][threadIdx.x] +
                  aux_s[2][threadIdx.x] + aux_s[3][threadIdx.x];
        atomicAdd(&ws_sums[threadIdx.x], s);
    }
}

__global__ void finalize_aux(const float* __restrict__ ws_sums,
                             float* __restrict__ auxp, int N) {
    float v = ws_sums[threadIdx.x] / (float)N;
    float v2 = v * v;
#pragma unroll
    for (int off = 32; off; off >>= 1) v2 += __shfl_xor(v2, off);
    if (threadIdx.x == 0) *auxp = v2;
}

extern "C" void kernel_launch(void* const* d_in, const int* in_sizes, int n_in,
                              void* d_out, int out_size, void* d_ws, size_t ws_size,
                              hipStream_t stream) {
    const float* x = (const float*)d_in[0];
    const float* w = (const float*)d_in[1];
    float* out = (float*)d_out;
    const int N = in_sizes[0] / D_DIM;  // 16384
    const size_t NE = (size_t)N * E_DIM;
    float* logits = out + 2 * NE;       // logits region of d_out (accumulated in place)
    float* ws_sums = (float*)d_ws;      // 64 floats of scratch

    // 1) zero the atomic-accumulation target + aux scratch
    zero_kernel<<<dim3(512), dim3(256), 0, stream>>>(logits, ws_sums, (int)(NE / 4));
    // 2) split-D router GEMM, fp32 VALU, atomic accumulate
    dim3 g1(N / BT, D_DIM / DC);
    router_gemm<<<g1, dim3(256), 0, stream>>>(x, w, logits);
    // 3) softmax + top-2 + scatter + per-expert sums
    postprocess<<<dim3(N / 64), dim3(256), 0, stream>>>(logits, out, ws_sums, N);
    // 4) aux loss
    finalize_aux<<<dim3(1), dim3(64), 0, stream>>>(ws_sums, out + 4 * NE, N);
}

// Round 3
// 276.108 us; speedup vs baseline: 1.5552x; 1.5552x over previous
//
#include <hip/hip_runtime.h>

#define D_DIM 2048
#define E_DIM 64
#define BT 256                   // tokens per block
#define DSPLIT 4
#define DCH (D_DIM / DSPLIT)     // 512
#define DK 32                    // depth per LDS tile
#define NTILE (DCH / DK)         // 16
#define XBYTES (BT * DK * 4)     // 32768
#define WBYTES (E_DIM * DK * 4)  // 8192
#define BUFB (XBYTES + WBYTES)   // 40960

typedef __attribute__((address_space(3))) char as3_char;
typedef __attribute__((address_space(1))) const char as1_char;

// C[t][e] partials: block (bx,by) computes tokens [bx*256,..+256) x all 64
// experts over D-chunk [by*512,..+512), stores into d_out region by (the
// disp/comb/logits/probs slots double as partial storage; postprocess
// consumes them in-place).
__global__ __launch_bounds__(256, 1) void router_gemm(
    const float* __restrict__ x, const float* __restrict__ w,
    float* __restrict__ out, int N) {
  __shared__ __align__(16) char lds[2][BUFB];
  const int tid = threadIdx.x;
  const int l = tid & 63;
  const int wv = tid >> 6;
  const int tbase = blockIdx.x * BT;
  const int dbase = blockIdx.y * DCH;

  // ---- staging: linear LDS dest (global_load_lds), source pre-swizzled so
  // that stored chunk s of row r holds global chunk s ^ (r&7). Per issue,
  // lane l -> row = base8 + (l>>3), stored chunk s = l&7, so the source
  // column chunk is (l&7) ^ (l>>3).
  const int scol = ((l & 7) ^ (l >> 3)) * 4;  // floats
  const float* xsrc[8];
#pragma unroll
  for (int q = 0; q < 8; ++q) {
    int row = (wv * 8 + q) * 8 + (l >> 3);
    xsrc[q] = x + (size_t)(tbase + row) * D_DIM + dbase + scol;
  }
  const float* wsrc[2];
#pragma unroll
  for (int q = 0; q < 2; ++q) {
    int e = (wv * 2 + q) * 8 + (l >> 3);
    wsrc[q] = w + (size_t)e * D_DIM + dbase + scol;
  }

  auto STAGE = [&](int b, int t) {
    const int d0 = t * DK;
#pragma unroll
    for (int q = 0; q < 8; ++q)
      __builtin_amdgcn_global_load_lds((as1_char*)(const char*)(xsrc[q] + d0),
                                       (as3_char*)&lds[b][(wv * 8 + q) * 1024],
                                       16, 0, 0);
#pragma unroll
    for (int q = 0; q < 2; ++q)
      __builtin_amdgcn_global_load_lds(
          (as1_char*)(const char*)(wsrc[q] + d0),
          (as3_char*)&lds[b][XBYTES + (wv * 2 + q) * 1024], 16, 0, 0);
  };

  // ---- compute mapping: thread (tg,eg) owns tokens {tg+32i} x experts
  // {eg*8+j}. Buffer-relative read offsets; the d4 XOR folds into the low
  // bits (row*128 is 128B-aligned, so base^(d4<<4) == row*128 + ((s^d4)<<4)).
  const int tg = tid & 31;
  const int eg = tid >> 5;
  int xoff[8], woff[8];
#pragma unroll
  for (int i = 0; i < 8; ++i) xoff[i] = (tg + 32 * i) * 128 + ((tg & 7) << 4);
#pragma unroll
  for (int j = 0; j < 8; ++j) woff[j] = XBYTES + (eg * 8 + j) * 128 + (j << 4);

  float acc[8][8];
#pragma unroll
  for (int i = 0; i < 8; ++i)
#pragma unroll
    for (int j = 0; j < 8; ++j) acc[i][j] = 0.f;

  STAGE(0, 0);
  asm volatile("s_waitcnt vmcnt(0)" ::: "memory");
  __syncthreads();

  int cur = 0;
  for (int t = 0; t < NTILE; ++t) {
    if (t + 1 < NTILE) STAGE(cur ^ 1, t + 1);  // prefetch under compute
    const char* buf = lds[cur];
#pragma unroll
    for (int d4 = 0; d4 < 8; ++d4) {
      const int dx = d4 << 4;
      float4 xv[8], wvv[8];
#pragma unroll
      for (int i = 0; i < 8; ++i)
        xv[i] = *(const float4*)(buf + (xoff[i] ^ dx));
#pragma unroll
      for (int j = 0; j < 8; ++j)
        wvv[j] = *(const float4*)(buf + (woff[j] ^ dx));
#pragma unroll
      for (int i = 0; i < 8; ++i)
#pragma unroll
        for (int j = 0; j < 8; ++j) {
          acc[i][j] = fmaf(xv[i].x, wvv[j].x, acc[i][j]);
          acc[i][j] = fmaf(xv[i].y, wvv[j].y, acc[i][j]);
          acc[i][j] = fmaf(xv[i].z, wvv[j].z, acc[i][j]);
          acc[i][j] = fmaf(xv[i].w, wvv[j].w, acc[i][j]);
        }
    }
    asm volatile("s_waitcnt vmcnt(0)" ::: "memory");
    __syncthreads();
    cur ^= 1;
  }

  // partial store: region = blockIdx.y, contiguous experts -> 2 float4/row
  float* part = out + (size_t)blockIdx.y * ((size_t)N * E_DIM);
#pragma unroll
  for (int i = 0; i < 8; ++i) {
    size_t o = (size_t)(tbase + tg + 32 * i) * E_DIM + eg * 8;
    *(float4*)(part + o) = make_float4(acc[i][0], acc[i][1], acc[i][2], acc[i][3]);
    *(float4*)(part + o + 4) = make_float4(acc[i][4], acc[i][5], acc[i][6], acc[i][7]);
  }
}

__global__ __launch_bounds__(256) void postprocess(float* out, float* ws, int N) {
  const int lane = threadIdx.x & 63;
  const int wv = threadIdx.x >> 6;
  const size_t NE = (size_t)N * E_DIM;
  float* disp = out;             // holds partial 0 on entry
  float* comb = out + NE;        // partial 1
  float* logits_o = out + 2 * NE;  // partial 2
  float* probs_o = out + 3 * NE;   // partial 3
  float* idx_o = out + 4 * NE + 1;
  float* pn_o = out + 4 * NE + 1 + 2 * (size_t)N;

  float expsum = 0.f;  // per-lane (= per-expert) prob sum over this wave's tokens
  const int t0 = blockIdx.x * 64 + wv * 16;
  for (int k = 0; k < 16; ++k) {
    const size_t t = (size_t)(t0 + k);
    const size_t o = t * E_DIM + lane;
    float lv = (disp[o] + comb[o]) + (logits_o[o] + probs_o[o]);
    logits_o[o] = lv;  // all 4 partials for this token already read
    float m = lv;
#pragma unroll
    for (int off = 32; off; off >>= 1) m = fmaxf(m, __shfl_xor(m, off));
    float p = __expf(lv - m);
    float s = p;
#pragma unroll
    for (int off = 32; off; off >>= 1) s += __shfl_xor(s, off);
    float prob = p / s;
    probs_o[o] = prob;
    expsum += prob;

    // packed key: prob bits | (63-lane) -> lowest index wins ties (jax top_k)
    unsigned long long key =
        ((unsigned long long)__float_as_uint(prob) << 32) | (unsigned)(63 - lane);
    unsigned long long k1 = key;
#pragma unroll
    for (int off = 32; off; off >>= 1) {
      unsigned long long v = __shfl_xor(k1, off);
      if (v > k1) k1 = v;
    }
    int i1 = 63 - (int)(k1 & 63);
    unsigned long long k2 = (lane == i1) ? 0ull : key;
#pragma unroll
    for (int off = 32; off; off >>= 1) {
      unsigned long long v = __shfl_xor(k2, off);
      if (v > k2) k2 = v;
    }
    int i2 = 63 - (int)(k2 & 63);
    float p1 = __uint_as_float((unsigned)(k1 >> 32));
    float p2 = __uint_as_float((unsigned)(k2 >> 32));
    float inv = 1.0f / (p1 + p2);
    float pn1 = p1 * inv, pn2 = p2 * inv;
    float dval = (lane == i1) ? pn1 : ((lane == i2) ? pn2 : 0.f);
    disp[o] = dval;
    comb[o] = dval;
    if (lane == 0) {
      idx_o[2 * t] = (float)i1;
      idx_o[2 * t + 1] = (float)i2;
      pn_o[2 * t] = pn1;
      pn_o[2 * t + 1] = pn2;
    }
  }

  __shared__ float aux_s[4][64];
  aux_s[wv][lane] = expsum;
  __syncthreads();
  if (threadIdx.x < 64) {
    float s = aux_s[0][threadIdx.x] + aux_s[1][threadIdx.x] +
              aux_s[2][threadIdx.x] + aux_s[3][threadIdx.x];
    ws[(size_t)blockIdx.x * 64 + threadIdx.x] = s;  // per-block expert partials
  }
}

__global__ __launch_bounds__(256) void finalize_aux(const float* __restrict__ ws,
                                                    float* __restrict__ auxp,
                                                    int nblocks, int N) {
  __shared__ float red[256];
  const int e = threadIdx.x & 63;
  const int part = threadIdx.x >> 6;
  float s = 0.f;
  for (int b = part; b < nblocks; b += 4) s += ws[(size_t)b * 64 + e];
  red[threadIdx.x] = s;
  __syncthreads();
  if (threadIdx.x < 64) {
    float tot = red[e] + red[64 + e] + red[128 + e] + red[192 + e];
    float pb = tot / (float)N;
    float v = pb * pb;  // aux = mean_e(E*pb^2) = sum_e pb^2
#pragma unroll
    for (int off = 32; off; off >>= 1) v += __shfl_xor(v, off);
    if (threadIdx.x == 0) *auxp = v;
  }
}

extern "C" void kernel_launch(void* const* d_in, const int* in_sizes, int n_in,
                              void* d_out, int out_size, void* d_ws, size_t ws_size,
                              hipStream_t stream) {
  (void)n_in; (void)out_size; (void)ws_size;
  const float* x = (const float*)d_in[0];
  const float* w = (const float*)d_in[1];
  float* out = (float*)d_out;
  const int N = in_sizes[0] / D_DIM;  // 16384
  const int npb = N / 64;             // postprocess blocks (256)

  dim3 gg(N / BT, DSPLIT);  // 64 x 4 = 256 blocks
  router_gemm<<<gg, dim3(256), 0, stream>>>(x, w, out, N);
  postprocess<<<dim3(npb), dim3(256), 0, stream>>>(out, (float*)d_ws, N);
  finalize_aux<<<dim3(1), dim3(256), 0, stream>>>((const float*)d_ws,
                                                  out + 4 * (size_t)N * E_DIM,
                                                  npb, N);
}